// Round 12
// baseline (128.940 us; speedup 1.0000x reference)
//
#include <hip/hip_runtime.h>
#include <math.h>

// ---------------------------------------------------------------------------
// Problem: B=64 batches. a_p = a@W1^T + b1 [64,1024]; b_p = b@W2^T + b2.
// cost[b,i,j] = (a_p[b,i]-b_p[b,j])^2 ; DTW DP R[i,j]=cost+min(diag,up,left);
// out[b] = R[1023,1023].
// ---------------------------------------------------------------------------

#define L 1024
#define BATCH 64

// ---------------- GEMM: out[b,i] = sum_k X[b,k]*W[i,k] (+ bias) ------------
__global__ __launch_bounds__(256) void proj_kernel(
    const float* __restrict__ a, const float* __restrict__ b,
    const float* __restrict__ W1, const float* __restrict__ b1,
    const float* __restrict__ W2, const float* __restrict__ b2,
    float* __restrict__ ap, float* __restrict__ bp, int KC) {
  int part = blockIdx.x >> 7;
  int sub = blockIdx.x & 127;
  const float* X;
  const float* W;
  const float* bias;
  float* out;
  int i0;
  if (sub < 64) {
    X = a; W = W1; bias = b1; out = ap + part * BATCH * L; i0 = sub * 16;
  } else {
    X = b; W = W2; bias = b2; out = bp + part * BATCH * L; i0 = (sub - 64) * 16;
  }

  __shared__ float a_s[64][33];
  __shared__ float w_s[16][33];

  int tid = threadIdx.x;
  int lane_b = tid & 63;
  int iq = tid >> 6;

  float acc[4] = {0.f, 0.f, 0.f, 0.f};

  int kbeg = part * KC;
  int kend = kbeg + KC;
  for (int k0 = kbeg; k0 < kend; k0 += 32) {
    {
      int row = tid >> 2;
      int kl = (tid & 3) * 8;
      const float4* src = reinterpret_cast<const float4*>(&X[row * L + k0 + kl]);
      float4 v0 = src[0];
      float4 v1 = src[1];
      a_s[row][kl + 0] = v0.x; a_s[row][kl + 1] = v0.y;
      a_s[row][kl + 2] = v0.z; a_s[row][kl + 3] = v0.w;
      a_s[row][kl + 4] = v1.x; a_s[row][kl + 5] = v1.y;
      a_s[row][kl + 6] = v1.z; a_s[row][kl + 7] = v1.w;
    }
    {
      int row = tid >> 4;
      int kl = (tid & 15) * 2;
      float2 v = *reinterpret_cast<const float2*>(&W[(i0 + row) * L + k0 + kl]);
      w_s[row][kl] = v.x;
      w_s[row][kl + 1] = v.y;
    }
    __syncthreads();
    #pragma unroll 8
    for (int kl = 0; kl < 32; ++kl) {
      float av = a_s[lane_b][kl];
      #pragma unroll
      for (int m = 0; m < 4; ++m) {
        acc[m] += av * w_s[iq * 4 + m][kl];
      }
    }
    __syncthreads();
  }

  #pragma unroll
  for (int m = 0; m < 4; ++m) {
    int i = i0 + iq * 4 + m;
    float bv = (part == 0) ? bias[i] : 0.f;
    out[lane_b * L + i] = acc[m] + bv;
  }
}

// ---------------- DTW: 4 waves/batch, register-resident ap feed ------------
// Lane (w,t) owns CPL=4 columns from (w*64+t)*4; delay D = w*OFF + t rows.
// Step s: lane processes row i = s-D. Steady-state step: 2 DPP + cndmask +
// 4 sub + 4 min3 + 4 fma; NO LDS, NO branches, NO SGPR traffic.
// KEY FIX vs R10: the 32 per-group ap values are loaded through VOLATILE
// LDS reads + sched_barrier(0), which the compiler cannot sink into the
// step loop (R10's plain loads were sunk -> hidden per-step ds_read +
// lgkmcnt stall; VGPR_Count=32 proved apf[] never lived in registers).
// Group = KBAR=32 steps. Per group: 32 pinned ds_reads (apf), one
// exec-masked ds_read row (ring feed), one exec-masked ds_write row
// (producer flush), one __syncthreads().
// GAP = OFF-63 = 32 = KBAR: boundary row r is produced+flushed exactly one
// group before the consumer's group-start load reads it; ring slot reuse
// distance = 64 steps = 2 groups -> no hazard. Ramp/drain garbage slots are
// discarded by the row-validity predicate.

#define NW 4
#define CPL 4
#define KBAR 32
#define OFF 95                       // 64 + 31 -> GAP = 32
#define DMAX (OFF * (NW - 1) + 63)   // 348
#define NG 43                        // ceil((L + DMAX) / KBAR)
#define NSTEPS (NG * KBAR)           // 1376
#define APPAD (DMAX + NSTEPS + 64)   // 1788

__device__ __forceinline__ float dpp_shr1(float v, float old) {
  // wave_shr:1, bound_ctrl=0: lane i <- lane i-1; lane 0 <- old[lane 0].
  int r = __builtin_amdgcn_update_dpp(__float_as_int(old), __float_as_int(v),
                                      0x138, 0xf, 0xf, false);
  return __int_as_float(r);
}

__device__ __forceinline__ float dpp_shl1(float v) {
  // wave_shl:1: lane i <- lane i+1; lane 63 keeps its value.
  int r = __builtin_amdgcn_update_dpp(__float_as_int(v), __float_as_int(v),
                                      0x130, 0xf, 0xf, false);
  return __int_as_float(r);
}

__device__ __forceinline__ float min3f(float x, float y, float z) {
  float r;
  asm("v_min3_f32 %0, %1, %2, %3" : "=v"(r) : "v"(x), "v"(y), "v"(z));
  return r;
}

__global__ __launch_bounds__(256, 1) void dtw_kernel(
    const float* __restrict__ app, const float* __restrict__ bpp,
    float* __restrict__ out, int parts) {
  const int b = blockIdx.x;
  const int tid = threadIdx.x;
  const int w = tid >> 6;
  const int t = tid & 63;
  const int woff = w * OFF;
  const int D = woff + t;
  const float INF = INFINITY;

  __shared__ float ap_pad[APPAD];
  __shared__ float ring[NW - 1][64];

  // ap_pad[DMAX + i] = sum_p ap_part[p][b,i]; zero skirts.
  for (int idx = tid; idx < APPAD; idx += 256) {
    int src = idx - DMAX;
    float v = 0.f;
    if ((unsigned)src < (unsigned)L) {
      v = app[b * L + src];
      for (int p = 1; p < parts; ++p) v += app[p * BATCH * L + b * L + src];
    }
    ap_pad[idx] = v;
  }

  float4 bv = *reinterpret_cast<const float4*>(&bpp[b * L + tid * CPL]);
  for (int p = 1; p < parts; ++p) {
    float4 u = *reinterpret_cast<const float4*>(
        &bpp[p * BATCH * L + b * L + tid * CPL]);
    bv.x += u.x; bv.y += u.y; bv.z += u.z; bv.w += u.w;
  }
  const float bpv0 = bv.x, bpv1 = bv.y, bpv2 = bv.z, bpv3 = bv.w;

  float p0 = INF, p1 = INF, p2 = INF, p3 = INF;  // prev-row cells
  float right = INF, prev_left = INF;
  float vprod = INF;
  // wave 0 boundary feed: lane0=0 seeds R[0,0]'s left at the first step;
  // afterwards shl1 walks INF down (lane 63 self-keeps INF forever).
  float ringchunk = (w == 0 && t == 0) ? 0.f : INF;
  // Per-lane volatile pointer: forces group-start loads to stay loads at
  // group start (not sunk into the step loop).
  volatile const float* apl = &ap_pad[DMAX - D];  // apl[s] == ap[b, s-D]

  __syncthreads();

  // One 32-step group. PRED: row-range predicate (ramp/drain). FIRSTG: the
  // first group carries the one-time diag fixup for column -1 of row 1.
#define DTW_GROUP(s0v, PRED, FIRSTG)                                         \
  {                                                                          \
    const int s0 = (s0v);                                                    \
    float apf[KBAR];                                                         \
    _Pragma("unroll")                                                        \
    for (int k = 0; k < KBAR; ++k) apf[k] = apl[s0 + k];  /* volatile */     \
    if (w > 0 && t < KBAR)                                                   \
      ringchunk = ring[w - 1][(s0 - woff + t) & 63];                         \
    __builtin_amdgcn_sched_barrier(0);  /* pin loads at group start */       \
    _Pragma("unroll")                                                        \
    for (int k = 0; k < KBAR; ++k) {                                         \
      float left = dpp_shr1(right, ringchunk);                               \
      ringchunk = dpp_shl1(ringchunk);                                       \
      int ii = s0 + k - D;                                                   \
      if (!(PRED) || ((unsigned)ii < (unsigned)L)) {                         \
        float dprev = prev_left;                                             \
        if ((FIRSTG) && k == 1 && w == 0 && t == 0) dprev = INF;             \
        prev_left = left;                                                    \
        float apv = apf[k];                                                  \
        float d0 = apv - bpv0, d1 = apv - bpv1;                              \
        float d2 = apv - bpv2, d3 = apv - bpv3;                              \
        float x = left, bb;                                                  \
        bb = min3f(p0, dprev, x); x = __builtin_fmaf(d0, d0, bb);            \
        dprev = p0; p0 = x;                                                  \
        bb = min3f(p1, dprev, x); x = __builtin_fmaf(d1, d1, bb);            \
        dprev = p1; p1 = x;                                                  \
        bb = min3f(p2, dprev, x); x = __builtin_fmaf(d2, d2, bb);            \
        dprev = p2; p2 = x;                                                  \
        bb = min3f(p3, dprev, x); x = __builtin_fmaf(d3, d3, bb);            \
        p3 = x;                                                              \
        right = x;                                                           \
      }                                                                      \
      vprod = dpp_shl1(vprod);                                               \
      vprod = (t == 63) ? right : vprod;                                     \
    }                                                                        \
    if (w < NW - 1 && t >= 64 - KBAR)                                        \
      ring[w][(s0 + t - woff - (63 + KBAR)) & 63] = vprod;                   \
    __syncthreads();                                                         \
  }

  // Ramp: groups 0..10 (steps 0..351 cover s < DMAX=348, predicated).
  for (int g = 0; g < 11; ++g) DTW_GROUP(g * KBAR, true, g == 0);
  // Steady: groups 11..31 (steps 352..1023; every lane's i in [0,L)).
  for (int g = 11; g < 32; ++g) DTW_GROUP(g * KBAR, false, false);
  // Drain: groups 32..42 (steps 1024..1375; last active step 1371).
  for (int g = 32; g < NG; ++g) DTW_GROUP(g * KBAR, true, false);
#undef DTW_GROUP

  if (tid == NW * 64 - 1) out[b] = right;  // R[1023,1023]
}

extern "C" void kernel_launch(void* const* d_in, const int* in_sizes, int n_in,
                              void* d_out, int out_size, void* d_ws, size_t ws_size,
                              hipStream_t stream) {
  const float* a  = (const float*)d_in[0];
  const float* b  = (const float*)d_in[1];
  const float* W1 = (const float*)d_in[2];
  const float* b1 = (const float*)d_in[3];
  const float* W2 = (const float*)d_in[4];
  const float* b2 = (const float*)d_in[5];
  float* out = (float*)d_out;

  size_t per_part = (size_t)2 * BATCH * L * sizeof(float);
  int parts = 1;
  if (ws_size >= 4 * per_part) parts = 4;
  else if (ws_size >= 2 * per_part) parts = 2;

  float* ap = (float*)d_ws;                    // parts x [BATCH, L]
  float* bp = ap + (size_t)parts * BATCH * L;  // parts x [BATCH, L]

  proj_kernel<<<128 * parts, 256, 0, stream>>>(a, b, W1, b1, W2, b2,
                                               ap, bp, L / parts);
  dtw_kernel<<<BATCH, 256, 0, stream>>>(ap, bp, out, parts);
}

// Round 13
// 122.940 us; speedup vs baseline: 1.0488x; 1.0488x over previous
//
#include <hip/hip_runtime.h>
#include <math.h>

// ---------------------------------------------------------------------------
// Problem: B=64 batches. a_p = a@W1^T + b1 [64,1024]; b_p = b@W2^T + b2.
// cost[b,i,j] = (a_p[b,i]-b_p[b,j])^2 ; DTW DP R[i,j]=cost+min(diag,up,left);
// out[b] = R[1023,1023].
// ---------------------------------------------------------------------------

#define L 1024
#define BATCH 64

// ---------------- GEMM: out[b,i] = sum_k X[b,k]*W[i,k] (+ bias) ------------
__global__ __launch_bounds__(256) void proj_kernel(
    const float* __restrict__ a, const float* __restrict__ b,
    const float* __restrict__ W1, const float* __restrict__ b1,
    const float* __restrict__ W2, const float* __restrict__ b2,
    float* __restrict__ ap, float* __restrict__ bp, int KC) {
  int part = blockIdx.x >> 7;
  int sub = blockIdx.x & 127;
  const float* X;
  const float* W;
  const float* bias;
  float* out;
  int i0;
  if (sub < 64) {
    X = a; W = W1; bias = b1; out = ap + part * BATCH * L; i0 = sub * 16;
  } else {
    X = b; W = W2; bias = b2; out = bp + part * BATCH * L; i0 = (sub - 64) * 16;
  }

  __shared__ float a_s[64][33];
  __shared__ float w_s[16][33];

  int tid = threadIdx.x;
  int lane_b = tid & 63;
  int iq = tid >> 6;

  float acc[4] = {0.f, 0.f, 0.f, 0.f};

  int kbeg = part * KC;
  int kend = kbeg + KC;
  for (int k0 = kbeg; k0 < kend; k0 += 32) {
    {
      int row = tid >> 2;
      int kl = (tid & 3) * 8;
      const float4* src = reinterpret_cast<const float4*>(&X[row * L + k0 + kl]);
      float4 v0 = src[0];
      float4 v1 = src[1];
      a_s[row][kl + 0] = v0.x; a_s[row][kl + 1] = v0.y;
      a_s[row][kl + 2] = v0.z; a_s[row][kl + 3] = v0.w;
      a_s[row][kl + 4] = v1.x; a_s[row][kl + 5] = v1.y;
      a_s[row][kl + 6] = v1.z; a_s[row][kl + 7] = v1.w;
    }
    {
      int row = tid >> 4;
      int kl = (tid & 15) * 2;
      float2 v = *reinterpret_cast<const float2*>(&W[(i0 + row) * L + k0 + kl]);
      w_s[row][kl] = v.x;
      w_s[row][kl + 1] = v.y;
    }
    __syncthreads();
    #pragma unroll 8
    for (int kl = 0; kl < 32; ++kl) {
      float av = a_s[lane_b][kl];
      #pragma unroll
      for (int m = 0; m < 4; ++m) {
        acc[m] += av * w_s[iq * 4 + m][kl];
      }
    }
    __syncthreads();
  }

  #pragma unroll
  for (int m = 0; m < 4; ++m) {
    int i = i0 + iq * 4 + m;
    float bv = (part == 0) ? bias[i] : 0.f;
    out[lane_b * L + i] = acc[m] + bv;
  }
}

// ---------------- DTW: 4 waves/batch, register-pinned ap feed --------------
// Lane (w,t) owns CPL=4 columns from (w*64+t)*4; delay D = w*OFF + t rows.
// Step s: lane processes row i = s-D. Steady-state step: 3 DPP + cndmask +
// 4 sub + 4 min3 + 4 fma; NO LDS, NO branches, NO waits.
// KEY FIX vs R10/R12: each per-group ap value is pinned to a VGPR by an
// empty volatile asm with a tied operand right after its plain LDS load.
// R10's plain loads were SUNK into the step loop (per-step ds_read+lgkmcnt,
// VGPR=32 proved it); R12's volatile loads SPILLED to scratch (VGPR still
// 32 + 37ms cold dispatch). The pin forces the value to materialize in a
// register at group start and stay there (zero instructions emitted);
// sched_barrier(0) keeps the load cluster from being rescheduled into the
// step loop (guide rules #17/#18).
// Group = KBAR=32 steps. Per group: 32 pinned ds_reads (apf), one
// exec-masked ds_read row (ring feed), one exec-masked ds_write row
// (producer flush), one __syncthreads().
// GAP = OFF-63 = 32 = KBAR: boundary row r is produced+flushed exactly one
// group before the consumer's group-start load reads it; ring slot reuse
// distance = 64 steps = 2 groups -> no hazard. Ramp/drain garbage slots are
// discarded by the row-validity predicate.

#define NW 4
#define CPL 4
#define KBAR 32
#define OFF 95                       // 64 + 31 -> GAP = 32
#define DMAX (OFF * (NW - 1) + 63)   // 348
#define NG 43                        // ceil((L + DMAX) / KBAR)
#define NSTEPS (NG * KBAR)           // 1376
#define APPAD (DMAX + NSTEPS + 64)   // 1788

__device__ __forceinline__ float dpp_shr1(float v, float old) {
  // wave_shr:1, bound_ctrl=0: lane i <- lane i-1; lane 0 <- old[lane 0].
  int r = __builtin_amdgcn_update_dpp(__float_as_int(old), __float_as_int(v),
                                      0x138, 0xf, 0xf, false);
  return __int_as_float(r);
}

__device__ __forceinline__ float dpp_shl1(float v) {
  // wave_shl:1: lane i <- lane i+1; lane 63 keeps its value.
  int r = __builtin_amdgcn_update_dpp(__float_as_int(v), __float_as_int(v),
                                      0x130, 0xf, 0xf, false);
  return __int_as_float(r);
}

__device__ __forceinline__ float min3f(float x, float y, float z) {
  float r;
  asm("v_min3_f32 %0, %1, %2, %3" : "=v"(r) : "v"(x), "v"(y), "v"(z));
  return r;
}

__global__ __launch_bounds__(256, 1) void dtw_kernel(
    const float* __restrict__ app, const float* __restrict__ bpp,
    float* __restrict__ out, int parts) {
  const int b = blockIdx.x;
  const int tid = threadIdx.x;
  const int w = tid >> 6;
  const int t = tid & 63;
  const int woff = w * OFF;
  const int D = woff + t;
  const float INF = INFINITY;

  __shared__ float ap_pad[APPAD];
  __shared__ float ring[NW - 1][64];

  // ap_pad[DMAX + i] = sum_p ap_part[p][b,i]; zero skirts.
  for (int idx = tid; idx < APPAD; idx += 256) {
    int src = idx - DMAX;
    float v = 0.f;
    if ((unsigned)src < (unsigned)L) {
      v = app[b * L + src];
      for (int p = 1; p < parts; ++p) v += app[p * BATCH * L + b * L + src];
    }
    ap_pad[idx] = v;
  }

  float4 bv = *reinterpret_cast<const float4*>(&bpp[b * L + tid * CPL]);
  for (int p = 1; p < parts; ++p) {
    float4 u = *reinterpret_cast<const float4*>(
        &bpp[p * BATCH * L + b * L + tid * CPL]);
    bv.x += u.x; bv.y += u.y; bv.z += u.z; bv.w += u.w;
  }
  const float bpv0 = bv.x, bpv1 = bv.y, bpv2 = bv.z, bpv3 = bv.w;

  float p0 = INF, p1 = INF, p2 = INF, p3 = INF;  // prev-row cells
  float right = INF, prev_left = INF;
  float vprod = INF;
  // wave 0 boundary feed: lane0=0 seeds R[0,0]'s left at the first step;
  // afterwards shl1 walks INF down (lane 63 self-keeps INF forever).
  float ringchunk = (w == 0 && t == 0) ? 0.f : INF;
  const float* apl = &ap_pad[DMAX - D];  // apl[s] == ap[b, s-D] (0 in skirts)

  __syncthreads();

  // One 32-step group. PRED: row-range predicate (ramp/drain). FIRSTG: the
  // first group carries the one-time diag fixup for column -1 of row 1.
#define DTW_GROUP(s0v, PRED, FIRSTG)                                         \
  {                                                                          \
    const int s0 = (s0v);                                                    \
    float apf[KBAR];                                                         \
    _Pragma("unroll")                                                        \
    for (int k = 0; k < KBAR; ++k) {                                         \
      apf[k] = apl[s0 + k];                                                  \
      asm volatile("" : "+v"(apf[k]));  /* pin value in a VGPR, 0 instrs */  \
    }                                                                        \
    if (w > 0 && t < KBAR)                                                   \
      ringchunk = ring[w - 1][(s0 - woff + t) & 63];                         \
    __builtin_amdgcn_sched_barrier(0);  /* nothing crosses into step loop */ \
    _Pragma("unroll")                                                        \
    for (int k = 0; k < KBAR; ++k) {                                         \
      float left = dpp_shr1(right, ringchunk);                               \
      ringchunk = dpp_shl1(ringchunk);                                       \
      int ii = s0 + k - D;                                                   \
      if (!(PRED) || ((unsigned)ii < (unsigned)L)) {                         \
        float dprev = prev_left;                                             \
        if ((FIRSTG) && k == 1 && w == 0 && t == 0) dprev = INF;             \
        prev_left = left;                                                    \
        float apv = apf[k];                                                  \
        float d0 = apv - bpv0, d1 = apv - bpv1;                              \
        float d2 = apv - bpv2, d3 = apv - bpv3;                              \
        float x = left, bb;                                                  \
        bb = min3f(p0, dprev, x); x = __builtin_fmaf(d0, d0, bb);            \
        dprev = p0; p0 = x;                                                  \
        bb = min3f(p1, dprev, x); x = __builtin_fmaf(d1, d1, bb);            \
        dprev = p1; p1 = x;                                                  \
        bb = min3f(p2, dprev, x); x = __builtin_fmaf(d2, d2, bb);            \
        dprev = p2; p2 = x;                                                  \
        bb = min3f(p3, dprev, x); x = __builtin_fmaf(d3, d3, bb);            \
        p3 = x;                                                              \
        right = x;                                                           \
      }                                                                      \
      vprod = dpp_shl1(vprod);                                               \
      vprod = (t == 63) ? right : vprod;                                     \
    }                                                                        \
    if (w < NW - 1 && t >= 64 - KBAR)                                        \
      ring[w][(s0 + t - woff - (63 + KBAR)) & 63] = vprod;                   \
    __syncthreads();                                                         \
  }

  // Ramp: groups 0..10 (steps 0..351 cover s < DMAX=348, predicated).
  for (int g = 0; g < 11; ++g) DTW_GROUP(g * KBAR, true, g == 0);
  // Steady: groups 11..31 (steps 352..1023; every lane's i in [0,L)).
  for (int g = 11; g < 32; ++g) DTW_GROUP(g * KBAR, false, false);
  // Drain: groups 32..42 (steps 1024..1375; last active step 1371).
  for (int g = 32; g < NG; ++g) DTW_GROUP(g * KBAR, true, false);
#undef DTW_GROUP

  if (tid == NW * 64 - 1) out[b] = right;  // R[1023,1023]
}

extern "C" void kernel_launch(void* const* d_in, const int* in_sizes, int n_in,
                              void* d_out, int out_size, void* d_ws, size_t ws_size,
                              hipStream_t stream) {
  const float* a  = (const float*)d_in[0];
  const float* b  = (const float*)d_in[1];
  const float* W1 = (const float*)d_in[2];
  const float* b1 = (const float*)d_in[3];
  const float* W2 = (const float*)d_in[4];
  const float* b2 = (const float*)d_in[5];
  float* out = (float*)d_out;

  size_t per_part = (size_t)2 * BATCH * L * sizeof(float);
  int parts = 1;
  if (ws_size >= 4 * per_part) parts = 4;
  else if (ws_size >= 2 * per_part) parts = 2;

  float* ap = (float*)d_ws;                    // parts x [BATCH, L]
  float* bp = ap + (size_t)parts * BATCH * L;  // parts x [BATCH, L]

  proj_kernel<<<128 * parts, 256, 0, stream>>>(a, b, W1, b1, W2, b2,
                                               ap, bp, L / parts);
  dtw_kernel<<<BATCH, 256, 0, stream>>>(ap, bp, out, parts);
}

// Round 15
// 96.818 us; speedup vs baseline: 1.3318x; 1.2698x over previous
//
#include <hip/hip_runtime.h>
#include <math.h>

// ---------------------------------------------------------------------------
// Problem: B=64 batches. a_p = a@W1^T + b1 [64,1024]; b_p = b@W2^T + b2.
// cost[b,i,j] = (a_p[b,i]-b_p[b,j])^2 ; DTW DP R[i,j]=cost+min(diag,up,left);
// out[b] = R[1023,1023].
// ---------------------------------------------------------------------------

#define L 1024
#define BATCH 64

// ---------------- GEMM: out[b,i] = sum_k X[b,k]*W[i,k] (+ bias) ------------
__global__ __launch_bounds__(256) void proj_kernel(
    const float* __restrict__ a, const float* __restrict__ b,
    const float* __restrict__ W1, const float* __restrict__ b1,
    const float* __restrict__ W2, const float* __restrict__ b2,
    float* __restrict__ ap, float* __restrict__ bp, int KC) {
  int part = blockIdx.x >> 7;
  int sub = blockIdx.x & 127;
  const float* X;
  const float* W;
  const float* bias;
  float* out;
  int i0;
  if (sub < 64) {
    X = a; W = W1; bias = b1; out = ap + part * BATCH * L; i0 = sub * 16;
  } else {
    X = b; W = W2; bias = b2; out = bp + part * BATCH * L; i0 = (sub - 64) * 16;
  }

  __shared__ float a_s[64][33];
  __shared__ float w_s[16][33];

  int tid = threadIdx.x;
  int lane_b = tid & 63;
  int iq = tid >> 6;

  float acc[4] = {0.f, 0.f, 0.f, 0.f};

  int kbeg = part * KC;
  int kend = kbeg + KC;
  for (int k0 = kbeg; k0 < kend; k0 += 32) {
    {
      int row = tid >> 2;
      int kl = (tid & 3) * 8;
      const float4* src = reinterpret_cast<const float4*>(&X[row * L + k0 + kl]);
      float4 v0 = src[0];
      float4 v1 = src[1];
      a_s[row][kl + 0] = v0.x; a_s[row][kl + 1] = v0.y;
      a_s[row][kl + 2] = v0.z; a_s[row][kl + 3] = v0.w;
      a_s[row][kl + 4] = v1.x; a_s[row][kl + 5] = v1.y;
      a_s[row][kl + 6] = v1.z; a_s[row][kl + 7] = v1.w;
    }
    {
      int row = tid >> 4;
      int kl = (tid & 15) * 2;
      float2 v = *reinterpret_cast<const float2*>(&W[(i0 + row) * L + k0 + kl]);
      w_s[row][kl] = v.x;
      w_s[row][kl + 1] = v.y;
    }
    __syncthreads();
    #pragma unroll 8
    for (int kl = 0; kl < 32; ++kl) {
      float av = a_s[lane_b][kl];
      #pragma unroll
      for (int m = 0; m < 4; ++m) {
        acc[m] += av * w_s[iq * 4 + m][kl];
      }
    }
    __syncthreads();
  }

  #pragma unroll
  for (int m = 0; m < 4; ++m) {
    int i = i0 + iq * 4 + m;
    float bv = (part == 0) ? bias[i] : 0.f;
    out[lane_b * L + i] = acc[m] + bv;
  }
}

// ---------------- DTW: 4 waves/batch, untied single-instr DPP step ---------
// Lane (w,t) owns CPL=4 columns from (w*64+t)*4; delay D = w*OFF + t rows.
// Step s: lane processes row i = s-D.
// All per-step DPP ops use bound_ctrl=1 (zero-fill) -> each is a SINGLE
// untied v_mov_b32_dpp (the tied old-operand form lowers to mov+dpp with
// RAW hazard wait-states; one sat on the cross-step critical path).
//   shifted = dpp_shr1_z(right)          // 1 instr, lane0 <- 0 (masked off)
//   left    = lane0 ? ringchunk : shifted
//   ringchunk = dpp_shl1_z(ringchunk)    // zero-fills lane 63
//   vprod     = dpp_shl1_z(vprod)        // lane63 overwritten by capture
// R14 BUG FIX: wave 0 never reloads ringchunk, so the zeros injected at
// lane 63 walked down to lane 0 after 63 steps (group >= 2) and fed left=0
// at the row boundary (absmax 27). Fix: re-init wave-0 ringchunk to INF at
// every group start (one masked mov outside the step loop); the very first
// group seeds lane (0,0) with 0 for R[0,0]. Consumer waves are unaffected
// (lanes 0..31 reloaded each group; lane 0 only reads walked lanes k<32).
// Group = KBAR=32 steps; per group: apf loads, one exec-masked ring read,
// one exec-masked ring write, one __syncthreads(). GAP = OFF-63 = 32 = KBAR
// (production exactly one barrier-ordered group before consumption; slot
// reuse distance 2 groups). Ramp/drain garbage discarded by PRED.

#define NW 4
#define CPL 4
#define KBAR 32
#define OFF 95                       // 64 + 31 -> GAP = 32
#define DMAX (OFF * (NW - 1) + 63)   // 348
#define NG 43                        // ceil((L + DMAX) / KBAR)
#define NSTEPS (NG * KBAR)           // 1376
#define APPAD (DMAX + NSTEPS + 64)   // 1788

__device__ __forceinline__ float dpp_shr1_z(float v) {
  // wave_shr:1, bound_ctrl=1: lane i <- lane i-1; lane 0 <- 0. One instr.
  int r = __builtin_amdgcn_update_dpp(0, __float_as_int(v), 0x138, 0xf, 0xf,
                                      true);
  return __int_as_float(r);
}

__device__ __forceinline__ float dpp_shl1_z(float v) {
  // wave_shl:1, bound_ctrl=1: lane i <- lane i+1; lane 63 <- 0. One instr.
  int r = __builtin_amdgcn_update_dpp(0, __float_as_int(v), 0x130, 0xf, 0xf,
                                      true);
  return __int_as_float(r);
}

__device__ __forceinline__ float min3f(float x, float y, float z) {
  float r;
  asm("v_min3_f32 %0, %1, %2, %3" : "=v"(r) : "v"(x), "v"(y), "v"(z));
  return r;
}

__global__ __launch_bounds__(256, 1) void dtw_kernel(
    const float* __restrict__ app, const float* __restrict__ bpp,
    float* __restrict__ out, int parts) {
  const int b = blockIdx.x;
  const int tid = threadIdx.x;
  const int w = tid >> 6;
  const int t = tid & 63;
  const int woff = w * OFF;
  const int D = woff + t;
  const float INF = INFINITY;

  __shared__ float ap_pad[APPAD];
  __shared__ float ring[NW - 1][64];

  // ap_pad[DMAX + i] = sum_p ap_part[p][b,i]; zero skirts.
  for (int idx = tid; idx < APPAD; idx += 256) {
    int src = idx - DMAX;
    float v = 0.f;
    if ((unsigned)src < (unsigned)L) {
      v = app[b * L + src];
      for (int p = 1; p < parts; ++p) v += app[p * BATCH * L + b * L + src];
    }
    ap_pad[idx] = v;
  }

  float4 bv = *reinterpret_cast<const float4*>(&bpp[b * L + tid * CPL]);
  for (int p = 1; p < parts; ++p) {
    float4 u = *reinterpret_cast<const float4*>(
        &bpp[p * BATCH * L + b * L + tid * CPL]);
    bv.x += u.x; bv.y += u.y; bv.z += u.z; bv.w += u.w;
  }
  const float bpv0 = bv.x, bpv1 = bv.y, bpv2 = bv.z, bpv3 = bv.w;

  float p0 = INF, p1 = INF, p2 = INF, p3 = INF;  // prev-row cells
  float right = INF, prev_left = INF;
  float vprod = INF;
  float ringchunk = INF;  // set per group below
  const bool lane0 = (t == 0);
  const bool lane63 = (t == 63);
  const float* apl = &ap_pad[DMAX - D];  // apl[s] == ap[b, s-D] (0 in skirts)

  __syncthreads();

  // One 32-step group. PRED: row-range predicate (ramp/drain). FIRSTG: the
  // first group seeds R[0,0]'s left and carries the one-time diag fixup.
#define DTW_GROUP(s0v, PRED, FIRSTG)                                         \
  {                                                                          \
    const int s0 = (s0v);                                                    \
    float apf[KBAR];                                                         \
    _Pragma("unroll")                                                        \
    for (int k = 0; k < KBAR; ++k) apf[k] = apl[s0 + k];                     \
    if (w == 0)                                                              \
      ringchunk = ((FIRSTG) && lane0) ? 0.f : INF;  /* R14 bugfix */         \
    else if (t < KBAR)                                                       \
      ringchunk = ring[w - 1][(s0 - woff + t) & 63];                         \
    _Pragma("unroll")                                                        \
    for (int k = 0; k < KBAR; ++k) {                                         \
      float shifted = dpp_shr1_z(right);                                     \
      float left = lane0 ? ringchunk : shifted;                              \
      ringchunk = dpp_shl1_z(ringchunk);                                     \
      int ii = s0 + k - D;                                                   \
      if (!(PRED) || ((unsigned)ii < (unsigned)L)) {                         \
        float dprev = prev_left;                                             \
        if ((FIRSTG) && k == 1 && w == 0 && t == 0) dprev = INF;             \
        prev_left = left;                                                    \
        float apv = apf[k];                                                  \
        float d0 = apv - bpv0, d1 = apv - bpv1;                              \
        float d2 = apv - bpv2, d3 = apv - bpv3;                              \
        float x = left, bb;                                                  \
        bb = min3f(p0, dprev, x); x = __builtin_fmaf(d0, d0, bb);            \
        dprev = p0; p0 = x;                                                  \
        bb = min3f(p1, dprev, x); x = __builtin_fmaf(d1, d1, bb);            \
        dprev = p1; p1 = x;                                                  \
        bb = min3f(p2, dprev, x); x = __builtin_fmaf(d2, d2, bb);            \
        dprev = p2; p2 = x;                                                  \
        bb = min3f(p3, dprev, x); x = __builtin_fmaf(d3, d3, bb);            \
        p3 = x;                                                              \
        right = x;                                                           \
      }                                                                      \
      vprod = dpp_shl1_z(vprod);                                             \
      vprod = lane63 ? right : vprod;                                        \
    }                                                                        \
    if (w < NW - 1 && t >= 64 - KBAR)                                        \
      ring[w][(s0 + t - woff - (63 + KBAR)) & 63] = vprod;                   \
    __syncthreads();                                                         \
  }

  // Ramp: groups 0..10 (steps 0..351 cover s < DMAX=348, predicated).
  for (int g = 0; g < 11; ++g) DTW_GROUP(g * KBAR, true, g == 0);
  // Steady: groups 11..31 (steps 352..1023; every lane's i in [0,L)).
  for (int g = 11; g < 32; ++g) DTW_GROUP(g * KBAR, false, false);
  // Drain: groups 32..42 (steps 1024..1375; last active step 1371).
  for (int g = 32; g < NG; ++g) DTW_GROUP(g * KBAR, true, false);
#undef DTW_GROUP

  if (tid == NW * 64 - 1) out[b] = right;  // R[1023,1023]
}

extern "C" void kernel_launch(void* const* d_in, const int* in_sizes, int n_in,
                              void* d_out, int out_size, void* d_ws, size_t ws_size,
                              hipStream_t stream) {
  const float* a  = (const float*)d_in[0];
  const float* b  = (const float*)d_in[1];
  const float* W1 = (const float*)d_in[2];
  const float* b1 = (const float*)d_in[3];
  const float* W2 = (const float*)d_in[4];
  const float* b2 = (const float*)d_in[5];
  float* out = (float*)d_out;

  size_t per_part = (size_t)2 * BATCH * L * sizeof(float);
  int parts = 1;
  if (ws_size >= 4 * per_part) parts = 4;
  else if (ws_size >= 2 * per_part) parts = 2;

  float* ap = (float*)d_ws;                    // parts x [BATCH, L]
  float* bp = ap + (size_t)parts * BATCH * L;  // parts x [BATCH, L]

  proj_kernel<<<128 * parts, 256, 0, stream>>>(a, b, W1, b1, W2, b2,
                                               ap, bp, L / parts);
  dtw_kernel<<<BATCH, 256, 0, stream>>>(ap, bp, out, parts);
}